// Round 19
// baseline (76.636 us; speedup 1.0000x reference)
//
#include <hip/hip_runtime.h>
#include <math.h>

// ---------------------------------------------------------------------------
// NeuralNet_62045097558546 on MI355X (gfx950)
// 3x (GEMM+bias+ReLU+cmax -> soft-topk mask) -> GEMM+bias
// GEMMs: FP16 MFMA 2-TERM split precision (r18-verified, absmax 9.8e-4):
//   C = Ahi*Bhi + Ahi*Blo over K' = 2K; A stores HI only.
// FRAGMENT-ORDER BLOCKED LAYOUT: panel p (64 rows) -> tile t (32 k') ->
//   slot s = (m>>4)*64 + g*16 + (m&15) (8 halfs: row m, k-chunk g).
// GEMM K-loop: no LDS/barriers/atomics; compile-time 4-stage reg pipeline.
//
// Soft-topk: root of A(t)=400 via safeguarded log-Newton (r14), DPP
// reduces (r17), tol exit |A-400|<0.01 (r12).
// THIS ROUND: WARM START. Worst-row cost is the bisection phase when the
// trajectory crosses the saturated regime (A~500, A-S->0: Newton derivative
// vanishes -> 1 bit/iter). Layers solve the same equation on similar data:
// store each row's converged u=ln(t) (16KB) and start the next layer there
// (bracket/safeguard unchanged -> same root, tol-exit). L2/L3/fin should
// start inside the quadratic basin: ~1-4 iters, no bisection.
// ---------------------------------------------------------------------------

typedef __attribute__((ext_vector_type(8))) short short8;
typedef __attribute__((ext_vector_type(8))) _Float16 half8;
typedef __attribute__((ext_vector_type(4))) float f32x4;

__device__ __forceinline__ short f2h(float v) {
  _Float16 h = (_Float16)v;
  return *(short*)&h;
}
__device__ __forceinline__ float h2f(short s) {
  _Float16 h = *(_Float16*)&s;
  return (float)h;
}

// ---- DPP wave reductions (64 lanes, VALU-only, no LDS pipe) ----
template <int CTRL>
__device__ __forceinline__ float dpp_mov0(float v) {
  return __int_as_float(__builtin_amdgcn_update_dpp(
      0, __float_as_int(v), CTRL, 0xf, 0xf, true));  // invalid lanes -> 0
}
__device__ __forceinline__ float wave_sum(float v) {
  v += dpp_mov0<0x111>(v);   // row_shr:1
  v += dpp_mov0<0x112>(v);   // row_shr:2
  v += dpp_mov0<0x114>(v);   // row_shr:4
  v += dpp_mov0<0x118>(v);   // row_shr:8
  v += dpp_mov0<0x142>(v);   // row_bcast:15
  v += dpp_mov0<0x143>(v);   // row_bcast:31
  return __int_as_float(__builtin_amdgcn_readlane(__float_as_int(v), 63));
}
__device__ __forceinline__ float wave_max_nn(float v) {  // nonneg values
  v = fmaxf(v, dpp_mov0<0x111>(v));
  v = fmaxf(v, dpp_mov0<0x112>(v));
  v = fmaxf(v, dpp_mov0<0x114>(v));
  v = fmaxf(v, dpp_mov0<0x118>(v));
  v = fmaxf(v, dpp_mov0<0x142>(v));
  v = fmaxf(v, dpp_mov0<0x143>(v));
  return __int_as_float(__builtin_amdgcn_readlane(__float_as_int(v), 63));
}

struct MegaArgs {
  const float *x, *W1, *b1, *W2, *b2, *W3, *b3, *W4, *b4;
  const int* sparse;
  float* out;
  short *Ablk, *B1blk, *B2blk, *B3blk, *Hmblk;
  float *H, *bp, *cmaxA, *uWarm;
};

// store 8 fp16 hi values (16B)
__device__ __forceinline__ void store8h(short* dst, const float* v) {
  short hi[8];
  #pragma unroll
  for (int i = 0; i < 8; ++i) hi[i] = f2h(v[i]);
  *(uint4*)dst = *(const uint4*)hi;
}
// store hi + lo pair (for B operands)
__device__ __forceinline__ void store16h(short* dstHi, short* dstLo,
                                         const float* v) {
  short hi[8], lo[8];
  #pragma unroll
  for (int i = 0; i < 8; ++i) {
    hi[i] = f2h(v[i]);
    lo[i] = f2h(v[i] - h2f(hi[i]));
  }
  *(uint4*)dstHi = *(const uint4*)hi;
  *(uint4*)dstLo = *(const uint4*)lo;
}

#define LDF(t, va, vb)                                                   \
  do {                                                                   \
    const int ta_ = ((t) < NTK) ? (t) : (t) - NTK;                       \
    const short* Ag_ = Abase + (size_t)ta_ * 2048;                       \
    const short* Bg_ = Bbase + (size_t)(t) * 2048;                       \
    va[0] = *(const short8*)(Ag_);                                       \
    va[1] = *(const short8*)(Ag_ + 512);                                 \
    va[2] = *(const short8*)(Ag_ + 1024);                                \
    va[3] = *(const short8*)(Ag_ + 1536);                                \
    vb[0] = *(const short8*)(Bg_);                                       \
    vb[1] = *(const short8*)(Bg_ + 512);                                 \
    vb[2] = *(const short8*)(Bg_ + 1024);                                \
    vb[3] = *(const short8*)(Bg_ + 1536);                                \
  } while (0)

#define CMP(va, vb)                                                      \
  do {                                                                   \
    _Pragma("unroll")                                                    \
    for (int s_ = 0; s_ < 4; ++s_)                                       \
      _Pragma("unroll")                                                  \
      for (int u_ = 0; u_ < 4; ++u_)                                     \
        acc[s_][u_] = __builtin_amdgcn_mfma_f32_16x16x32_f16(            \
            *(const half8*)&va[s_], *(const half8*)&vb[u_],              \
            acc[s_][u_], 0, 0, 0);                                       \
  } while (0)

// ---- GEMM kernel: one 64x64 tile/block, per-wave split-K' (K'=2K),
//      4-stage register pipeline ----
template <int NTK>
__global__ __launch_bounds__(256, 2) void gemm_k(
    const short* __restrict__ Ablk, const short* __restrict__ Bblk,
    const float* __restrict__ bp, float* __restrict__ H,
    float* __restrict__ cmaxArr)
{
  __shared__ __align__(16) float fl[8704];   // epilogue: 4 x [32][68]
  __shared__ float red4[4];

  const int tid  = threadIdx.x;
  const int lane = tid & 63, w = tid >> 6;
  const int rg = lane >> 4, rl = lane & 15;

  // by fast: XCD (blockIdx%8) keeps its 8 A row-panels L2-resident.
  const int by = blockIdx.x & 63, bx = blockIdx.x >> 6;
  const int row0 = by * 64, col0 = bx * 64;

  const short* Abase = Ablk + (size_t)by * NTK * 2048 + lane * 8;       // hi only
  const short* Bbase = Bblk + (size_t)bx * (2 * NTK) * 2048 + lane * 8; // [hi|lo]

  constexpr int nt = (2 * NTK) >> 2;   // 16 (K=1024) / 8 (K=512)
  const int t0 = w * nt;

  f32x4 acc[4][4];
  #pragma unroll
  for (int s = 0; s < 4; ++s)
    #pragma unroll
    for (int u = 0; u < 4; ++u)
      acc[s][u] = (f32x4){0.f, 0.f, 0.f, 0.f};

  short8 A0[4], B0[4], A1[4], B1[4], A2[4], B2[4], A3[4], B3[4];
  LDF(t0 + 0, A0, B0);
  LDF(t0 + 1, A1, B1);
  LDF(t0 + 2, A2, B2);
  LDF(t0 + 3, A3, B3);
  #pragma unroll
  for (int i = 0; i < nt; i += 4) {
    CMP(A0, B0);
    if (i + 4 < nt) LDF(t0 + i + 4, A0, B0);
    CMP(A1, B1);
    if (i + 5 < nt) LDF(t0 + i + 5, A1, B1);
    CMP(A2, B2);
    if (i + 6 < nt) LDF(t0 + i + 6, A2, B2);
    CMP(A3, B3);
    if (i + 7 < nt) LDF(t0 + i + 7, A3, B3);
  }

  // ---- epilogue: 2-pass cross-wave split-K reduce + bias + relu + cmax ----
  float lmax = 0.0f;
  #pragma unroll
  for (int p = 0; p < 2; ++p) {
    if (p == 1) __syncthreads();
    #pragma unroll
    for (int sp = 0; sp < 2; ++sp) {
      const int s = p * 2 + sp;
      #pragma unroll
      for (int u = 0; u < 4; ++u)
        #pragma unroll
        for (int i = 0; i < 4; ++i)
          fl[w * 2176 + (sp * 16 + rg * 4 + i) * 68 + u * 16 + rl] = acc[s][u][i];
    }
    __syncthreads();

    const int rloc = w * 8 + (lane >> 3);      // 0..31
    const int c0 = (lane & 7) * 8;
    f32x4 s0 = {0.f, 0.f, 0.f, 0.f}, s1 = {0.f, 0.f, 0.f, 0.f};
    #pragma unroll
    for (int q = 0; q < 4; ++q) {
      const float* src = fl + q * 2176 + rloc * 68 + c0;
      s0 += *(const f32x4*)src;
      s1 += *(const f32x4*)(src + 4);
    }
    const int gr = row0 + p * 32 + rloc;
    const int gc = col0 + c0;
    const f32x4 bb0 = *(const f32x4*)&bp[gc];
    const f32x4 bb1 = *(const f32x4*)&bp[gc + 4];
    f32x4 o0, o1;
    #pragma unroll
    for (int i = 0; i < 4; ++i) {
      o0[i] = fmaxf(s0[i] + bb0[i], 0.f);
      o1[i] = fmaxf(s1[i] + bb1[i], 0.f);
    }
    float* Hp = H + (size_t)gr * 512 + gc;
    *(f32x4*)Hp = o0;
    *(f32x4*)(Hp + 4) = o1;
    #pragma unroll
    for (int i = 0; i < 4; ++i) {
      if (gc + i < 500) {
        const float v = o0[i], vm = v - 1.0f;
        lmax = fmaxf(lmax, fmaxf(v * v, vm * vm));
      }
      if (gc + 4 + i < 500) {
        const float v = o1[i], vm = v - 1.0f;
        lmax = fmaxf(lmax, fmaxf(v * v, vm * vm));
      }
    }
  }

  lmax = wave_max_nn(lmax);
  if (lane == 0) red4[w] = lmax;
  __syncthreads();
  if (tid == 0)
    cmaxArr[blockIdx.x] =
        fmaxf(fmaxf(red4[0], red4[1]), fmaxf(red4[2], red4[3]));
}

// ---- prep: job = one 4KB tile; thread = slot -> fully coalesced writes ----
// jobs: x-hi 2048 | W1 256 | W2 128 | W3 128 | bias 1 => 2561
__global__ __launch_bounds__(256) void prep_k(MegaArgs a)
{
  const int sIdx = threadIdx.x;
  const int m = ((sIdx >> 6) << 4) | (sIdx & 15);
  const int g = (sIdx >> 4) & 3;
  for (int job = blockIdx.x; job < 2561; job += gridDim.x) {
    if (job < 2048) {                       // x -> Ablk (HI only)
      const int p = job >> 5, t = job & 31;
      const float* src = a.x + (size_t)(p * 64 + m) * 1024 + t * 32 + g * 8;
      float v[8];
      const f32x4 u0 = *(const f32x4*)src;
      const f32x4 u1 = *(const f32x4*)(src + 4);
      #pragma unroll
      for (int i = 0; i < 4; ++i) { v[i] = u0[i]; v[4 + i] = u1[i]; }
      short* d = a.Ablk + ((size_t)p * 32 + t) * 2048 + sIdx * 8;
      store8h(d, v);
    } else if (job < 2304) {                // W1 -> B1blk [hi|lo]
      const int j = job - 2048;
      const int p = j >> 5, t = j & 31;
      const int n = p * 64 + m;
      float v[8];
      #pragma unroll
      for (int i = 0; i < 8; ++i) {
        const int k = t * 32 + g * 8 + i;
        v[i] = (n < 500) ? a.W1[(size_t)k * 500 + n] : 0.0f;
      }
      short* d = a.B1blk + ((size_t)p * 64 + t) * 2048 + sIdx * 8;
      store16h(d, d + 65536, v);            // lo: +32*2048
    } else if (job < 2560) {                // W2/W3 -> B2blk/B3blk [hi|lo]
      const int j = (job - 2304) & 127;
      const bool isW3 = (job >= 2432);
      const float* W = isW3 ? a.W3 : a.W2;
      short* Bb = isW3 ? a.B3blk : a.B2blk;
      const int p = j >> 4, t = j & 15;
      const int n = p * 64 + m;
      float v[8];
      #pragma unroll
      for (int i = 0; i < 8; ++i) {
        const int k = t * 32 + g * 8 + i;
        v[i] = (n < 500 && k < 500) ? W[(size_t)k * 500 + n] : 0.0f;
      }
      short* d = Bb + ((size_t)p * 32 + t) * 2048 + sIdx * 8;
      store16h(d, d + 32768, v);            // lo: +16*2048
    } else {                                // bias pad bp[3][512]
      for (int r = 0; r < 6; ++r) {
        const int idx = r * 256 + threadIdx.x;
        const int L = idx >> 9, c = idx & 511;
        const float* src = (L == 0) ? a.b1 : (L == 1) ? a.b2 : a.b3;
        a.bp[idx] = (c < 500) ? src[c] : 0.0f;
      }
    }
  }
}

// ---- per-row soft-topk solve (r14 solver, DPP reduces, warm start) ----
// WARM: start u at uWarm[row] (prev layer's root; bracket/safeguard intact).
// Always stores the converged u to uWarm[row] for the next layer.
template <bool WARM>
__device__ __forceinline__ void softk_row(
    const float* __restrict__ H, const float* __restrict__ cmaxArr,
    float* __restrict__ uWarm, float s, int row, int lane, float* mh)
{
  const f32x4 cc0 = *(const f32x4*)&cmaxArr[lane * 8];
  const f32x4 cc1 = *(const f32x4*)&cmaxArr[lane * 8 + 4];
  float cmax = fmaxf(fmaxf(fmaxf(cc0[0], cc0[1]), fmaxf(cc0[2], cc0[3])),
                     fmaxf(fmaxf(cc1[0], cc1[1]), fmaxf(cc1[2], cc1[3])));
  cmax = wave_max_nn(cmax);

  const float inv = 1.0f / (0.1f * cmax);
  const float* Hr = H + (size_t)row * 512 + lane * 8;
  const f32x4 u0 = *(const f32x4*)Hr;
  const f32x4 u1 = *(const f32x4*)(Hr + 4);
  float h[8] = {u0[0], u0[1], u0[2], u0[3], u1[0], u1[1], u1[2], u1[3]};
  float R[8];
  #pragma unroll
  for (int j = 0; j < 8; ++j) R[j] = __expf((2.0f * h[j] - 1.0f) * inv);

  const int nval = min(max(500 - lane * 8, 0), 8);

  float u_lo = -40.0f, u_hi = 40.0f;
  float uu = 0.0f;
  if (WARM) {
    uu = uWarm[row];                       // same value all lanes
    uu = fminf(fmaxf(uu, -39.0f), 39.0f);
  }
  float t = __expf(uu), A = 0.0f;
  for (int it = 0; it < 50; ++it) {
    float Ap = 0.0f, Sp = 0.0f;
    #pragma unroll
    for (int j = 0; j < 8; ++j) {
      float wv = __builtin_amdgcn_rcpf(fmaf(t, R[j], 1.0f));
      if (j >= nval) wv = 0.0f;
      Ap += wv;
      Sp = fmaf(wv, wv, Sp);
    }
    A = wave_sum(Ap);
    const float S = wave_sum(Sp);
    if (fabsf(A - 400.0f) < 0.01f || it == 49) break;  // converged (tol)
    if (A > 400.0f) u_lo = uu; else u_hi = uu;
    const float du = (A - 400.0f) * __builtin_amdgcn_rcpf(A - S);
    float un = uu + du;
    if (!(un > u_lo && un < u_hi)) un = 0.5f * (u_lo + u_hi);  // bisect
    uu = un;
    t = __expf(uu);
  }
  if (lane == 0) uWarm[row] = uu;          // seed for next layer

  const float kA = 400.0f / A;
  #pragma unroll
  for (int j = 0; j < 8; ++j) {
    const float wv = __builtin_amdgcn_rcpf(fmaf(t, R[j], 1.0f));
    float o = h[j] * (s * (kA * wv) + (1.0f - s));
    if (j >= nval) o = 0.0f;
    mh[j] = o;
  }
}

// ---- middle sinkhorn: 8 rows/block (512 thr), LDS transpose ->
//      128B-contiguous blocked HI-only writes ----
template <bool WARM>
__global__ __launch_bounds__(512) void sinkhorn_mid(
    MegaArgs a, const float* __restrict__ cmaxArr, short* __restrict__ outBlk)
{
  __shared__ float lf[8 * 64 * 9];     // [j][kc][row] stride-9 (18.4KB)
  const int w    = threadIdx.x >> 6;
  const int lane = threadIdx.x & 63;
  const int r0   = blockIdx.x * 8;
  const int row  = r0 + w;

  float mh[8];
  softk_row<WARM>(a.H, cmaxArr, a.uWarm, (float)a.sparse[0], row, lane, mh);

  #pragma unroll
  for (int j = 0; j < 8; ++j)
    lf[j * 576 + lane * 9 + w] = mh[j];
  __syncthreads();

  // phase 2: half-wave = one tile; lanes -> (g, rr) -> 128B-contiguous runs
  const int p     = r0 >> 6;
  const int q     = (r0 & 63) >> 4;
  const int base8 = r0 & 8;
  const int half = lane >> 5, lh = lane & 31;
  const int tt = 2 * w + half;
  const int g = (lh >> 3) & 3, rr = lh & 7;

  float v[8];
  #pragma unroll
  for (int j = 0; j < 8; ++j)
    v[j] = lf[j * 576 + (tt * 4 + g) * 9 + rr];

  const int slot = q * 64 + g * 16 + base8 + rr;
  short* o = outBlk + ((size_t)p * 16 + tt) * 2048 + slot * 8;
  store8h(o, v);                       // hi only; panel stride 16 tiles
}

// ---- final sinkhorn fused with [500x10] GEMM + b4 ----
__global__ __launch_bounds__(256) void sinkhorn_fin(
    MegaArgs a, const float* __restrict__ cmaxArr)
{
  const int w    = threadIdx.x >> 6;
  const int lane = threadIdx.x & 63;
  const int row  = blockIdx.x * 4 + w;

  float mh[8];
  softk_row<true>(a.H, cmaxArr, a.uWarm, (float)a.sparse[0], row, lane, mh);

  const int nval = min(max(500 - lane * 8, 0), 8);
  float acc[10];
  #pragma unroll
  for (int o = 0; o < 10; ++o) acc[o] = 0.0f;
  const float* Wr = a.W4 + (size_t)lane * 80;
  #pragma unroll
  for (int j = 0; j < 8; ++j) {
    if (j < nval) {
      #pragma unroll
      for (int o = 0; o < 10; ++o)
        acc[o] = fmaf(mh[j], Wr[j * 10 + o], acc[o]);
    }
  }
  #pragma unroll
  for (int o = 0; o < 10; ++o) acc[o] = wave_sum(acc[o]);
  if (lane == 0) {
    #pragma unroll
    for (int o = 0; o < 10; ++o)
      a.out[(size_t)row * 10 + o] = acc[o] + a.b4[o];
  }
}

extern "C" void kernel_launch(void* const* d_in, const int* in_sizes, int n_in,
                              void* d_out, int out_size, void* d_ws, size_t ws_size,
                              hipStream_t stream)
{
  char* ws = (char*)d_ws;

  MegaArgs a;
  a.x  = (const float*)d_in[0];
  a.W1 = (const float*)d_in[1];
  a.b1 = (const float*)d_in[2];
  a.W2 = (const float*)d_in[3];
  a.b2 = (const float*)d_in[4];
  a.W3 = (const float*)d_in[5];
  a.b3 = (const float*)d_in[6];
  a.W4 = (const float*)d_in[7];
  a.b4 = (const float*)d_in[8];
  a.sparse = (const int*)d_in[9];
  a.out = (float*)d_out;

  a.cmaxA = (float*)ws;                                      // [3][512]
  a.bp    = (float*)(ws + 8192);                             // [3][512]
  a.uWarm = (float*)(ws + 16384);                            // [4096]
  a.Ablk  = (short*)(ws + 32768);                            // 64x32 tiles = 8MB
  a.B1blk = a.Ablk  + (size_t)64 * 32 * 2048;                // 2MB
  a.B2blk = a.B1blk + (size_t)8 * 64 * 2048;                 // 1MB
  a.B3blk = a.B2blk + (size_t)8 * 32 * 2048;                 // 1MB
  a.H     = (float*)(a.B3blk + (size_t)8 * 32 * 2048);       // 8MB
  a.Hmblk = (short*)(a.H + (size_t)4096 * 512);              // 4MB

  prep_k<<<512, 256, 0, stream>>>(a);
  gemm_k<32><<<512, 256, 0, stream>>>(a.Ablk, a.B1blk, a.bp, a.H, a.cmaxA);
  sinkhorn_mid<false><<<512, 512, 0, stream>>>(a, a.cmaxA, a.Hmblk);
  gemm_k<16><<<512, 256, 0, stream>>>(a.Hmblk, a.B2blk, a.bp + 512, a.H,
                                      a.cmaxA + 512);
  sinkhorn_mid<true><<<512, 512, 0, stream>>>(a, a.cmaxA + 512, a.Hmblk);
  gemm_k<16><<<512, 256, 0, stream>>>(a.Hmblk, a.B3blk, a.bp + 1024, a.H,
                                      a.cmaxA + 1024);
  sinkhorn_fin<<<1024, 256, 0, stream>>>(a, a.cmaxA + 1024);
}

// Round 20
// 61.514 us; speedup vs baseline: 1.2458x; 1.2458x over previous
//
#include <hip/hip_runtime.h>
#include <math.h>

// ---------------------------------------------------------------------------
// NeuralNet_62045097558546 on MI355X (gfx950)
// 3x (GEMM+bias+ReLU+cmax -> soft-topk mask) -> GEMM+bias
// GEMMs: PURE FP16 MFMA, 1-term: C = fp16(A)*fp16(B), f32 accumulate.
//   Error budget: A-lo + B-lo dropped, independent -> absmax ~ sqrt(2) x
//   r18's 2-term 9.77e-4 ~ 1.4e-3 (threshold 3.3e-3). K' = K (no remap).
// H (pre-mask activations) stored FP16 (one extra 2^-11 rounding; the
//   next GEMM's A-operand was already fp16-hi). cmax from f32 epilogue vals.
// FRAGMENT-ORDER BLOCKED LAYOUT: panel p (64 rows) -> tile t (32 k) ->
//   slot s = (m>>4)*64 + g*16 + (m&15) (8 halfs: row m, k-chunk g).
// GEMM K-loop: no LDS/barriers/atomics; compile-time 4-stage reg pipeline.
//
// Soft-topk: root of A(t)=400 via safeguarded log-Newton (r14), DPP
// reduces (r17), tol exit |A-400|<0.01 (r12). Warm start REVERTED (r19:
// -3us regression; iteration-tail theories all null r14/r15/r17/r19).
// ---------------------------------------------------------------------------

typedef __attribute__((ext_vector_type(8))) short short8;
typedef __attribute__((ext_vector_type(8))) _Float16 half8;
typedef __attribute__((ext_vector_type(4))) float f32x4;

__device__ __forceinline__ short f2h(float v) {
  _Float16 h = (_Float16)v;
  return *(short*)&h;
}
__device__ __forceinline__ float h2f(short s) {
  _Float16 h = *(_Float16*)&s;
  return (float)h;
}

// ---- DPP wave reductions (64 lanes, VALU-only, no LDS pipe) ----
template <int CTRL>
__device__ __forceinline__ float dpp_mov0(float v) {
  return __int_as_float(__builtin_amdgcn_update_dpp(
      0, __float_as_int(v), CTRL, 0xf, 0xf, true));  // invalid lanes -> 0
}
__device__ __forceinline__ float wave_sum(float v) {
  v += dpp_mov0<0x111>(v);   // row_shr:1
  v += dpp_mov0<0x112>(v);   // row_shr:2
  v += dpp_mov0<0x114>(v);   // row_shr:4
  v += dpp_mov0<0x118>(v);   // row_shr:8
  v += dpp_mov0<0x142>(v);   // row_bcast:15
  v += dpp_mov0<0x143>(v);   // row_bcast:31
  return __int_as_float(__builtin_amdgcn_readlane(__float_as_int(v), 63));
}
__device__ __forceinline__ float wave_max_nn(float v) {  // nonneg values
  v = fmaxf(v, dpp_mov0<0x111>(v));
  v = fmaxf(v, dpp_mov0<0x112>(v));
  v = fmaxf(v, dpp_mov0<0x114>(v));
  v = fmaxf(v, dpp_mov0<0x118>(v));
  v = fmaxf(v, dpp_mov0<0x142>(v));
  v = fmaxf(v, dpp_mov0<0x143>(v));
  return __int_as_float(__builtin_amdgcn_readlane(__float_as_int(v), 63));
}

struct MegaArgs {
  const float *x, *W1, *b1, *W2, *b2, *W3, *b3, *W4, *b4;
  const int* sparse;
  float* out;
  short *Ablk, *B1blk, *B2blk, *B3blk, *Hmblk;
  short *H;                       // fp16 pre-mask activations
  float *bp, *cmaxA;
};

// store 8 fp16 values (16B)
__device__ __forceinline__ void store8h(short* dst, const float* v) {
  short hi[8];
  #pragma unroll
  for (int i = 0; i < 8; ++i) hi[i] = f2h(v[i]);
  *(uint4*)dst = *(const uint4*)hi;
}

#define LDF(t, va, vb)                                                   \
  do {                                                                   \
    const short* Ag_ = Abase + (size_t)(t) * 2048;                       \
    const short* Bg_ = Bbase + (size_t)(t) * 2048;                       \
    va[0] = *(const short8*)(Ag_);                                       \
    va[1] = *(const short8*)(Ag_ + 512);                                 \
    va[2] = *(const short8*)(Ag_ + 1024);                                \
    va[3] = *(const short8*)(Ag_ + 1536);                                \
    vb[0] = *(const short8*)(Bg_);                                       \
    vb[1] = *(const short8*)(Bg_ + 512);                                 \
    vb[2] = *(const short8*)(Bg_ + 1024);                                \
    vb[3] = *(const short8*)(Bg_ + 1536);                                \
  } while (0)

#define CMP(va, vb)                                                      \
  do {                                                                   \
    _Pragma("unroll")                                                    \
    for (int s_ = 0; s_ < 4; ++s_)                                       \
      _Pragma("unroll")                                                  \
      for (int u_ = 0; u_ < 4; ++u_)                                     \
        acc[s_][u_] = __builtin_amdgcn_mfma_f32_16x16x32_f16(            \
            *(const half8*)&va[s_], *(const half8*)&vb[u_],              \
            acc[s_][u_], 0, 0, 0);                                       \
  } while (0)

// ---- GEMM kernel: one 64x64 tile/block, per-wave split-K (K'=K),
//      4-stage register pipeline. NTK = K/32 tiles per panel (A and B). ----
template <int NTK>
__global__ __launch_bounds__(256, 2) void gemm_k(
    const short* __restrict__ Ablk, const short* __restrict__ Bblk,
    const float* __restrict__ bp, short* __restrict__ H,
    float* __restrict__ cmaxArr)
{
  __shared__ __align__(16) float fl[8704];   // epilogue: 4 x [32][68]
  __shared__ float red4[4];

  const int tid  = threadIdx.x;
  const int lane = tid & 63, w = tid >> 6;
  const int rg = lane >> 4, rl = lane & 15;

  // by fast: XCD (blockIdx%8) keeps its 8 A row-panels L2-resident.
  const int by = blockIdx.x & 63, bx = blockIdx.x >> 6;
  const int row0 = by * 64, col0 = bx * 64;

  const short* Abase = Ablk + (size_t)by * NTK * 2048 + lane * 8;
  const short* Bbase = Bblk + (size_t)bx * NTK * 2048 + lane * 8;

  constexpr int nt = NTK >> 2;         // 8 (K=1024) / 4 (K=512)
  const int t0 = w * nt;

  f32x4 acc[4][4];
  #pragma unroll
  for (int s = 0; s < 4; ++s)
    #pragma unroll
    for (int u = 0; u < 4; ++u)
      acc[s][u] = (f32x4){0.f, 0.f, 0.f, 0.f};

  short8 A0[4], B0[4], A1[4], B1[4], A2[4], B2[4], A3[4], B3[4];
  LDF(t0 + 0, A0, B0);
  LDF(t0 + 1, A1, B1);
  LDF(t0 + 2, A2, B2);
  LDF(t0 + 3, A3, B3);
  #pragma unroll
  for (int i = 0; i < nt; i += 4) {
    CMP(A0, B0);
    if (i + 4 < nt) LDF(t0 + i + 4, A0, B0);
    CMP(A1, B1);
    if (i + 5 < nt) LDF(t0 + i + 5, A1, B1);
    CMP(A2, B2);
    if (i + 6 < nt) LDF(t0 + i + 6, A2, B2);
    CMP(A3, B3);
    if (i + 7 < nt) LDF(t0 + i + 7, A3, B3);
  }

  // ---- epilogue: 2-pass cross-wave split-K reduce + bias + relu + cmax ----
  float lmax = 0.0f;
  #pragma unroll
  for (int p = 0; p < 2; ++p) {
    if (p == 1) __syncthreads();
    #pragma unroll
    for (int sp = 0; sp < 2; ++sp) {
      const int s = p * 2 + sp;
      #pragma unroll
      for (int u = 0; u < 4; ++u)
        #pragma unroll
        for (int i = 0; i < 4; ++i)
          fl[w * 2176 + (sp * 16 + rg * 4 + i) * 68 + u * 16 + rl] = acc[s][u][i];
    }
    __syncthreads();

    const int rloc = w * 8 + (lane >> 3);      // 0..31
    const int c0 = (lane & 7) * 8;
    f32x4 s0 = {0.f, 0.f, 0.f, 0.f}, s1 = {0.f, 0.f, 0.f, 0.f};
    #pragma unroll
    for (int q = 0; q < 4; ++q) {
      const float* src = fl + q * 2176 + rloc * 68 + c0;
      s0 += *(const f32x4*)src;
      s1 += *(const f32x4*)(src + 4);
    }
    const int gr = row0 + p * 32 + rloc;
    const int gc = col0 + c0;
    const f32x4 bb0 = *(const f32x4*)&bp[gc];
    const f32x4 bb1 = *(const f32x4*)&bp[gc + 4];
    float o[8];
    #pragma unroll
    for (int i = 0; i < 4; ++i) {
      o[i]     = fmaxf(s0[i] + bb0[i], 0.f);
      o[4 + i] = fmaxf(s1[i] + bb1[i], 0.f);
    }
    store8h(H + (size_t)gr * 512 + gc, o);     // fp16 H
    #pragma unroll
    for (int i = 0; i < 8; ++i) {
      if (gc + i < 500) {
        const float v = o[i], vm = v - 1.0f;
        lmax = fmaxf(lmax, fmaxf(v * v, vm * vm));
      }
    }
  }

  lmax = wave_max_nn(lmax);
  if (lane == 0) red4[w] = lmax;
  __syncthreads();
  if (tid == 0)
    cmaxArr[blockIdx.x] =
        fmaxf(fmaxf(red4[0], red4[1]), fmaxf(red4[2], red4[3]));
}

// ---- prep: job = one 4KB tile; thread = slot -> fully coalesced writes ----
// jobs: x 2048 | W1 256 | W2 128 | W3 128 | bias 1 => 2561 (all hi-only)
__global__ __launch_bounds__(256) void prep_k(MegaArgs a)
{
  const int sIdx = threadIdx.x;
  const int m = ((sIdx >> 6) << 4) | (sIdx & 15);
  const int g = (sIdx >> 4) & 3;
  for (int job = blockIdx.x; job < 2561; job += gridDim.x) {
    if (job < 2048) {                       // x -> Ablk
      const int p = job >> 5, t = job & 31;
      const float* src = a.x + (size_t)(p * 64 + m) * 1024 + t * 32 + g * 8;
      float v[8];
      const f32x4 u0 = *(const f32x4*)src;
      const f32x4 u1 = *(const f32x4*)(src + 4);
      #pragma unroll
      for (int i = 0; i < 4; ++i) { v[i] = u0[i]; v[4 + i] = u1[i]; }
      short* d = a.Ablk + ((size_t)p * 32 + t) * 2048 + sIdx * 8;
      store8h(d, v);
    } else if (job < 2304) {                // W1 -> B1blk
      const int j = job - 2048;
      const int p = j >> 5, t = j & 31;
      const int n = p * 64 + m;
      float v[8];
      #pragma unroll
      for (int i = 0; i < 8; ++i) {
        const int k = t * 32 + g * 8 + i;
        v[i] = (n < 500) ? a.W1[(size_t)k * 500 + n] : 0.0f;
      }
      short* d = a.B1blk + ((size_t)p * 32 + t) * 2048 + sIdx * 8;
      store8h(d, v);
    } else if (job < 2560) {                // W2/W3 -> B2blk/B3blk
      const int j = (job - 2304) & 127;
      const bool isW3 = (job >= 2432);
      const float* W = isW3 ? a.W3 : a.W2;
      short* Bb = isW3 ? a.B3blk : a.B2blk;
      const int p = j >> 4, t = j & 15;
      const int n = p * 64 + m;
      float v[8];
      #pragma unroll
      for (int i = 0; i < 8; ++i) {
        const int k = t * 32 + g * 8 + i;
        v[i] = (n < 500 && k < 500) ? W[(size_t)k * 500 + n] : 0.0f;
      }
      short* d = Bb + ((size_t)p * 16 + t) * 2048 + sIdx * 8;
      store8h(d, v);
    } else {                                // bias pad bp[3][512]
      for (int r = 0; r < 6; ++r) {
        const int idx = r * 256 + threadIdx.x;
        const int L = idx >> 9, c = idx & 511;
        const float* src = (L == 0) ? a.b1 : (L == 1) ? a.b2 : a.b3;
        a.bp[idx] = (c < 500) ? src[c] : 0.0f;
      }
    }
  }
}

// ---- per-row soft-topk solve (r14 solver, DPP reduces, fp16 H read) ----
__device__ __forceinline__ void softk_row(
    const short* __restrict__ H, const float* __restrict__ cmaxArr,
    float s, int row, int lane, float* mh)
{
  const f32x4 cc0 = *(const f32x4*)&cmaxArr[lane * 8];
  const f32x4 cc1 = *(const f32x4*)&cmaxArr[lane * 8 + 4];
  float cmax = fmaxf(fmaxf(fmaxf(cc0[0], cc0[1]), fmaxf(cc0[2], cc0[3])),
                     fmaxf(fmaxf(cc1[0], cc1[1]), fmaxf(cc1[2], cc1[3])));
  cmax = wave_max_nn(cmax);

  const float inv = 1.0f / (0.1f * cmax);
  const short* Hr = H + (size_t)row * 512 + lane * 8;
  const uint4 raw = *(const uint4*)Hr;
  const short* hs = (const short*)&raw;
  float h[8], R[8];
  #pragma unroll
  for (int j = 0; j < 8; ++j) h[j] = h2f(hs[j]);
  #pragma unroll
  for (int j = 0; j < 8; ++j) R[j] = __expf((2.0f * h[j] - 1.0f) * inv);

  const int nval = min(max(500 - lane * 8, 0), 8);

  float u_lo = -40.0f, u_hi = 40.0f;
  float uu = 0.0f, t = 1.0f, A = 0.0f;
  for (int it = 0; it < 50; ++it) {
    float Ap = 0.0f, Sp = 0.0f;
    #pragma unroll
    for (int j = 0; j < 8; ++j) {
      float wv = __builtin_amdgcn_rcpf(fmaf(t, R[j], 1.0f));
      if (j >= nval) wv = 0.0f;
      Ap += wv;
      Sp = fmaf(wv, wv, Sp);
    }
    A = wave_sum(Ap);
    const float S = wave_sum(Sp);
    if (fabsf(A - 400.0f) < 0.01f || it == 49) break;  // converged (tol)
    if (A > 400.0f) u_lo = uu; else u_hi = uu;
    const float du = (A - 400.0f) * __builtin_amdgcn_rcpf(A - S);
    float un = uu + du;
    if (!(un > u_lo && un < u_hi)) un = 0.5f * (u_lo + u_hi);  // bisect
    uu = un;
    t = __expf(uu);
  }

  const float kA = 400.0f / A;
  #pragma unroll
  for (int j = 0; j < 8; ++j) {
    const float wv = __builtin_amdgcn_rcpf(fmaf(t, R[j], 1.0f));
    float o = h[j] * (s * (kA * wv) + (1.0f - s));
    if (j >= nval) o = 0.0f;
    mh[j] = o;
  }
}

// ---- middle sinkhorn: 8 rows/block (512 thr), LDS transpose ->
//      128B-contiguous blocked fp16 writes ----
__global__ __launch_bounds__(512) void sinkhorn_mid(
    MegaArgs a, const float* __restrict__ cmaxArr, short* __restrict__ outBlk)
{
  __shared__ float lf[8 * 64 * 9];     // [j][kc][row] stride-9 (18.4KB)
  const int w    = threadIdx.x >> 6;
  const int lane = threadIdx.x & 63;
  const int r0   = blockIdx.x * 8;
  const int row  = r0 + w;

  float mh[8];
  softk_row(a.H, cmaxArr, (float)a.sparse[0], row, lane, mh);

  #pragma unroll
  for (int j = 0; j < 8; ++j)
    lf[j * 576 + lane * 9 + w] = mh[j];
  __syncthreads();

  // phase 2: half-wave = one tile; lanes -> (g, rr) -> 128B-contiguous runs
  const int p     = r0 >> 6;
  const int q     = (r0 & 63) >> 4;
  const int base8 = r0 & 8;
  const int half = lane >> 5, lh = lane & 31;
  const int tt = 2 * w + half;
  const int g = (lh >> 3) & 3, rr = lh & 7;

  float v[8];
  #pragma unroll
  for (int j = 0; j < 8; ++j)
    v[j] = lf[j * 576 + (tt * 4 + g) * 9 + rr];

  const int slot = q * 64 + g * 16 + base8 + rr;
  short* o = outBlk + ((size_t)p * 16 + tt) * 2048 + slot * 8;
  store8h(o, v);                       // panel stride 16 tiles (fp16 hi)
}

// ---- final sinkhorn fused with [500x10] GEMM + b4 ----
__global__ __launch_bounds__(256) void sinkhorn_fin(
    MegaArgs a, const float* __restrict__ cmaxArr)
{
  const int w    = threadIdx.x >> 6;
  const int lane = threadIdx.x & 63;
  const int row  = blockIdx.x * 4 + w;

  float mh[8];
  softk_row(a.H, cmaxArr, (float)a.sparse[0], row, lane, mh);

  const int nval = min(max(500 - lane * 8, 0), 8);
  float acc[10];
  #pragma unroll
  for (int o = 0; o < 10; ++o) acc[o] = 0.0f;
  const float* Wr = a.W4 + (size_t)lane * 80;
  #pragma unroll
  for (int j = 0; j < 8; ++j) {
    if (j < nval) {
      #pragma unroll
      for (int o = 0; o < 10; ++o)
        acc[o] = fmaf(mh[j], Wr[j * 10 + o], acc[o]);
    }
  }
  #pragma unroll
  for (int o = 0; o < 10; ++o) acc[o] = wave_sum(acc[o]);
  if (lane == 0) {
    #pragma unroll
    for (int o = 0; o < 10; ++o)
      a.out[(size_t)row * 10 + o] = acc[o] + a.b4[o];
  }
}

extern "C" void kernel_launch(void* const* d_in, const int* in_sizes, int n_in,
                              void* d_out, int out_size, void* d_ws, size_t ws_size,
                              hipStream_t stream)
{
  char* ws = (char*)d_ws;

  MegaArgs a;
  a.x  = (const float*)d_in[0];
  a.W1 = (const float*)d_in[1];
  a.b1 = (const float*)d_in[2];
  a.W2 = (const float*)d_in[3];
  a.b2 = (const float*)d_in[4];
  a.W3 = (const float*)d_in[5];
  a.b3 = (const float*)d_in[6];
  a.W4 = (const float*)d_in[7];
  a.b4 = (const float*)d_in[8];
  a.sparse = (const int*)d_in[9];
  a.out = (float*)d_out;

  a.cmaxA = (float*)ws;                                      // [3][512]
  a.bp    = (float*)(ws + 8192);                             // [3][512]
  a.Ablk  = (short*)(ws + 16384);                            // 64x32 tiles = 8MB
  a.B1blk = a.Ablk  + (size_t)64 * 32 * 2048;                // 8x32 = 1MB
  a.B2blk = a.B1blk + (size_t)8 * 32 * 2048;                 // 8x16 = 512KB
  a.B3blk = a.B2blk + (size_t)8 * 16 * 2048;                 // 512KB
  a.H     = a.B3blk + (size_t)8 * 16 * 2048;                 // 4096x512 fp16 = 4MB
  a.Hmblk = a.H + (size_t)4096 * 512;                        // 64x16 tiles = 4MB

  prep_k<<<512, 256, 0, stream>>>(a);
  gemm_k<32><<<512, 256, 0, stream>>>(a.Ablk, a.B1blk, a.bp, a.H, a.cmaxA);
  sinkhorn_mid<<<512, 512, 0, stream>>>(a, a.cmaxA, a.Hmblk);
  gemm_k<16><<<512, 256, 0, stream>>>(a.Hmblk, a.B2blk, a.bp + 512, a.H,
                                      a.cmaxA + 512);
  sinkhorn_mid<<<512, 512, 0, stream>>>(a, a.cmaxA + 512, a.Hmblk);
  gemm_k<16><<<512, 256, 0, stream>>>(a.Hmblk, a.B3blk, a.bp + 1024, a.H,
                                      a.cmaxA + 1024);
  sinkhorn_fin<<<1024, 256, 0, stream>>>(a, a.cmaxA + 1024);
}